// Round 2
// baseline (141.397 us; speedup 1.0000x reference)
//
#include <hip/hip_runtime.h>
#include <hip/hip_bf16.h>

#define BATCH 8
#define NN    256
#define FIN   128
#define H1    4
#define C1    128
#define HC1   512   // H1*C1
#define NEG_SLOPE 0.2f

// ---------------- Kernel 1: h1 = x @ W1  ([B,256,128] @ [128,512]) ----------
// grid (32, 8), block 256. Each block: 8 rows x 512 cols.
__global__ void gemm1_kernel(const float* __restrict__ x,
                             const float* __restrict__ W1,
                             float* __restrict__ h1) {
    __shared__ float xs[8][FIN];
    const int b  = blockIdx.y;
    const int r0 = blockIdx.x * 8;
    const int t  = threadIdx.x;

    const float* xp = x + (b * NN + r0) * FIN;
    #pragma unroll
    for (int i = 0; i < 4; ++i) {
        int idx = t + i * 256;
        xs[idx >> 7][idx & 127] = xp[idx];
    }
    __syncthreads();

    float acc[8][2];
    #pragma unroll
    for (int r = 0; r < 8; ++r) { acc[r][0] = 0.f; acc[r][1] = 0.f; }

    for (int k = 0; k < FIN; ++k) {
        float w0 = W1[k * HC1 + t];
        float w1 = W1[k * HC1 + t + 256];
        #pragma unroll
        for (int r = 0; r < 8; ++r) {
            float xv = xs[r][k];
            acc[r][0] = fmaf(xv, w0, acc[r][0]);
            acc[r][1] = fmaf(xv, w1, acc[r][1]);
        }
    }
    #pragma unroll
    for (int r = 0; r < 8; ++r) {
        h1[(b * NN + r0 + r) * HC1 + t]       = acc[r][0];
        h1[(b * NN + r0 + r) * HC1 + t + 256] = acc[r][1];
    }
}

// ---------------- Kernel 1b: a_src1/a_dst1 wave reductions -------------------
// grid 2048 (one block per (b,n)), block 256 = 4 waves, wave w handles head w.
__global__ void areduce1_kernel(const float* __restrict__ h1,
                                const float* __restrict__ att_src,
                                const float* __restrict__ att_dst,
                                float* __restrict__ a_src,
                                float* __restrict__ a_dst) {
    const int bn   = blockIdx.x;
    const int t    = threadIdx.x;
    const int h    = t >> 6;
    const int lane = t & 63;

    const float* hp = h1 + bn * HC1 + h * C1;
    float v0 = hp[lane], v1 = hp[lane + 64];
    float s = v0 * att_src[h * C1 + lane] + v1 * att_src[h * C1 + lane + 64];
    float d = v0 * att_dst[h * C1 + lane] + v1 * att_dst[h * C1 + lane + 64];
    #pragma unroll
    for (int off = 32; off > 0; off >>= 1) {
        s += __shfl_down(s, off, 64);
        d += __shfl_down(d, off, 64);
    }
    if (lane == 0) {
        a_src[bn * H1 + h] = s;
        a_dst[bn * H1 + h] = d;
    }
}

// ---------------- Kernel 2: layer-1 softmax + aggregate + bias + relu --------
// grid (16 dst-tiles, 4 heads, 8 batch), block 256. DT=16 dsts per block.
__global__ void agg1_kernel(const float* __restrict__ h1,
                            const float* __restrict__ a_src,
                            const float* __restrict__ a_dst,
                            const float* __restrict__ b1,
                            float* __restrict__ hrelu) {
    __shared__ float s_as[NN];
    __shared__ float s_ad[16];
    __shared__ float sp[16][NN];
    __shared__ float red[16][17];
    __shared__ float s_m[16], s_den[16];

    const int b    = blockIdx.z;
    const int head = blockIdx.y;
    const int d0   = blockIdx.x * 16;
    const int t    = threadIdx.x;

    s_as[t] = a_src[(b * NN + t) * H1 + head];
    if (t < 16) s_ad[t] = a_dst[(b * NN + d0 + t) * H1 + head];
    __syncthreads();

    const int d = t >> 4;   // dst within tile (16 per block)
    const int l = t & 15;   // 16 threads per dst
    const float adst = s_ad[d];

    float mx = -1e30f;
    #pragma unroll
    for (int i = 0; i < 16; ++i) {
        int src = l + i * 16;
        float e = s_as[src] + adst;
        e = (e > 0.f) ? e : NEG_SLOPE * e;
        sp[d][src] = e;
        mx = fmaxf(mx, e);
    }
    red[d][l] = mx;
    __syncthreads();
    if (t < 16) {
        float m = red[t][0];
        #pragma unroll
        for (int i = 1; i < 16; ++i) m = fmaxf(m, red[t][i]);
        s_m[t] = m;
    }
    __syncthreads();

    const float m = s_m[d];
    float sum = 0.f;
    #pragma unroll
    for (int i = 0; i < 16; ++i) {
        int src = l + i * 16;
        float p = __expf(sp[d][src] - m);
        sp[d][src] = p;
        sum += p;
    }
    red[d][l] = sum;
    __syncthreads();
    if (t < 16) {
        float s = 0.f;
        #pragma unroll
        for (int i = 0; i < 16; ++i) s += red[t][i];
        s_den[t] = s + 1e-16f;
    }
    __syncthreads();

    // aggregation: out[dst, c] = sum_src p[dst][src] * h1[b, src, head*128+c]
    const int c = t & 127;
    const int g = t >> 7;   // 0 or 1 -> dsts g*8..g*8+7
    float acc[8];
    #pragma unroll
    for (int j = 0; j < 8; ++j) acc[j] = 0.f;

    const float* hbase = h1 + (size_t)(b * NN) * HC1 + head * C1 + c;
    for (int src = 0; src < NN; ++src) {
        float hv = hbase[(size_t)src * HC1];
        #pragma unroll
        for (int j = 0; j < 8; ++j)
            acc[j] = fmaf(sp[g * 8 + j][src], hv, acc[j]);
    }

    const float bias = b1[head * C1 + c];
    #pragma unroll
    for (int j = 0; j < 8; ++j) {
        int dst = d0 + g * 8 + j;
        float v = acc[j] / s_den[g * 8 + j] + bias;
        hrelu[(b * NN + dst) * HC1 + head * C1 + c] = fmaxf(v, 0.f);
    }
}

// ---------------- Kernel 3: h2 = hrelu @ W2  ([B,256,512] @ [512,128]) -------
// grid (32, 8), block 256. Each block: 8 rows x 128 cols.
__global__ void gemm2_kernel(const float* __restrict__ hrelu,
                             const float* __restrict__ W2,
                             float* __restrict__ h2) {
    __shared__ float xs[8][HC1];
    const int b  = blockIdx.y;
    const int r0 = blockIdx.x * 8;
    const int t  = threadIdx.x;

    const float* xp = hrelu + (size_t)(b * NN + r0) * HC1;
    #pragma unroll
    for (int i = 0; i < 16; ++i) {
        int idx = t + i * 256;
        xs[idx >> 9][idx & 511] = xp[idx];
    }
    __syncthreads();

    const int c  = t & 127;
    const int rg = t >> 7;  // 0/1 -> rows rg*4..rg*4+3
    float acc[4];
    #pragma unroll
    for (int i = 0; i < 4; ++i) acc[i] = 0.f;

    for (int k = 0; k < HC1; ++k) {
        float w = W2[k * FIN + c];
        #pragma unroll
        for (int i = 0; i < 4; ++i)
            acc[i] = fmaf(xs[rg * 4 + i][k], w, acc[i]);
    }
    #pragma unroll
    for (int i = 0; i < 4; ++i)
        h2[(b * NN + r0 + rg * 4 + i) * FIN + c] = acc[i];
}

// ---------------- Kernel 3b: a_src2/a_dst2 (single head) ---------------------
// grid 512 blocks, block 256 = 4 waves, wave per node.
__global__ void areduce2_kernel(const float* __restrict__ h2,
                                const float* __restrict__ att_src,
                                const float* __restrict__ att_dst,
                                float* __restrict__ a_src,
                                float* __restrict__ a_dst) {
    const int t    = threadIdx.x;
    const int bn   = blockIdx.x * 4 + (t >> 6);
    const int lane = t & 63;

    const float* hp = h2 + bn * FIN;
    float v0 = hp[lane], v1 = hp[lane + 64];
    float s = v0 * att_src[lane] + v1 * att_src[lane + 64];
    float d = v0 * att_dst[lane] + v1 * att_dst[lane + 64];
    #pragma unroll
    for (int off = 32; off > 0; off >>= 1) {
        s += __shfl_down(s, off, 64);
        d += __shfl_down(d, off, 64);
    }
    if (lane == 0) {
        a_src[bn] = s;
        a_dst[bn] = d;
    }
}

// ---------------- Kernel 4: layer-2 softmax + aggregate + bias ---------------
// grid (32 dst-tiles, 8 batch), block 256. DT=8 dsts per block.
__global__ void agg2_kernel(const float* __restrict__ h2,
                            const float* __restrict__ a_src,
                            const float* __restrict__ a_dst,
                            const float* __restrict__ b2,
                            float* __restrict__ out) {
    __shared__ float s_as[NN];
    __shared__ float s_ad[8];
    __shared__ float sp[8][NN];
    __shared__ float red[8][33];
    __shared__ float s_m[8], s_den[8];

    const int b  = blockIdx.y;
    const int d0 = blockIdx.x * 8;
    const int t  = threadIdx.x;

    s_as[t] = a_src[b * NN + t];
    if (t < 8) s_ad[t] = a_dst[b * NN + d0 + t];
    __syncthreads();

    const int d = t >> 5;   // dst within tile (8 per block)
    const int l = t & 31;   // 32 threads per dst
    const float adst = s_ad[d];

    float mx = -1e30f;
    #pragma unroll
    for (int i = 0; i < 8; ++i) {
        int src = l + i * 32;
        float e = s_as[src] + adst;
        e = (e > 0.f) ? e : NEG_SLOPE * e;
        sp[d][src] = e;
        mx = fmaxf(mx, e);
    }
    red[d][l] = mx;
    __syncthreads();
    if (t < 8) {
        float m = red[t][0];
        #pragma unroll
        for (int i = 1; i < 32; ++i) m = fmaxf(m, red[t][i]);
        s_m[t] = m;
    }
    __syncthreads();

    const float m = s_m[d];
    float sum = 0.f;
    #pragma unroll
    for (int i = 0; i < 8; ++i) {
        int src = l + i * 32;
        float p = __expf(sp[d][src] - m);
        sp[d][src] = p;
        sum += p;
    }
    red[d][l] = sum;
    __syncthreads();
    if (t < 8) {
        float s = 0.f;
        #pragma unroll
        for (int i = 0; i < 32; ++i) s += red[t][i];
        s_den[t] = s + 1e-16f;
    }
    __syncthreads();

    const int c = t & 127;
    const int g = t >> 7;   // 0/1 -> dsts g*4..g*4+3
    float acc[4];
    #pragma unroll
    for (int j = 0; j < 4; ++j) acc[j] = 0.f;

    const float* hbase = h2 + (size_t)(b * NN) * FIN + c;
    for (int src = 0; src < NN; ++src) {
        float hv = hbase[(size_t)src * FIN];
        #pragma unroll
        for (int j = 0; j < 4; ++j)
            acc[j] = fmaf(sp[g * 4 + j][src], hv, acc[j]);
    }

    const float bias = b2[c];
    #pragma unroll
    for (int j = 0; j < 4; ++j) {
        int dst = d0 + g * 4 + j;
        out[(b * NN + dst) * FIN + c] = acc[j] / s_den[g * 4 + j] + bias;
    }
}

// ---------------- launch -----------------------------------------------------
extern "C" void kernel_launch(void* const* d_in, const int* in_sizes, int n_in,
                              void* d_out, int out_size, void* d_ws, size_t ws_size,
                              hipStream_t stream) {
    const float* x    = (const float*)d_in[0];
    const float* W1   = (const float*)d_in[1];
    const float* as1  = (const float*)d_in[2];
    const float* ad1  = (const float*)d_in[3];
    const float* b1   = (const float*)d_in[4];
    const float* W2   = (const float*)d_in[5];
    const float* as2  = (const float*)d_in[6];
    const float* ad2  = (const float*)d_in[7];
    const float* b2   = (const float*)d_in[8];
    float* out = (float*)d_out;

    float* ws = (float*)d_ws;
    float* h1     = ws;                      // 8*256*512 = 1048576
    float* hrelu  = ws + 1048576;            // 1048576
    float* h2     = ws + 2097152;            // 262144
    float* a_src1 = ws + 2359296;            // 8192
    float* a_dst1 = ws + 2367488;            // 8192
    float* a_src2 = ws + 2375680;            // 2048
    float* a_dst2 = ws + 2377728;            // 2048

    gemm1_kernel<<<dim3(32, BATCH), 256, 0, stream>>>(x, W1, h1);
    areduce1_kernel<<<BATCH * NN, 256, 0, stream>>>(h1, as1, ad1, a_src1, a_dst1);
    agg1_kernel<<<dim3(16, H1, BATCH), 256, 0, stream>>>(h1, a_src1, a_dst1, b1, hrelu);
    gemm2_kernel<<<dim3(32, BATCH), 256, 0, stream>>>(hrelu, W2, h2);
    areduce2_kernel<<<BATCH * NN / 4, 256, 0, stream>>>(h2, as2, ad2, a_src2, a_dst2);
    agg2_kernel<<<dim3(32, BATCH), 256, 0, stream>>>(h2, a_src2, a_dst2, b2, out);
}